// Round 2
// baseline (129.710 us; speedup 1.0000x reference)
//
#include <hip/hip_runtime.h>

typedef __bf16 bf16x8 __attribute__((ext_vector_type(8)));
typedef __bf16 bf16x4 __attribute__((ext_vector_type(4)));
typedef float  floatx4 __attribute__((ext_vector_type(4)));
typedef float  f32x2   __attribute__((ext_vector_type(2)));

#define NENT 237
#define NREL 237
#define D 128
#define B_TRIPLES 16384
#define PITCH 72                          // 64 k + 8 pad: balanced banks for b128 frag reads
#define HALF_BYTES (128 * PITCH * 2)      // 18432 B = 18 chunks of 1024
#define HALF_CHUNKS 18

// ws layout (bytes)
#define WIMG_OFF 0
#define WIMG_BYTES (NREL * 2 * HALF_BYTES)             // 8,736,768
#define EIMG_OFF (WIMG_OFF + WIMG_BYTES)
#define EIMG_BYTES (4 * 128 * PITCH * 2)               // 73,728  [slab][kh][row][72]
#define PROJ_OFF (EIMG_OFF + EIMG_BYTES)
#define PROJ_BYTES (NREL * NENT * D * 2)               // 14,376,960 (bf16, permuted j)
#define REP2_OFF (PROJ_OFF + PROJ_BYTES)
#define REP2_N (NREL * 64)                             // float2 pairs
#define FCP2_OFF (REP2_OFF + REP2_N * 8)
#define FCP2_N (50 * 64)

__device__ __forceinline__ int jof(int pos) {          // stored pos -> original j
  return ((pos & 7) << 4) | (pos >> 3);
}

__device__ __forceinline__ void async_cp16(const void* g, void* l, int lane) {
  __builtin_amdgcn_global_load_lds(
      (const __attribute__((address_space(1))) void*)((const char*)g + lane * 16),
      (__attribute__((address_space(3))) void*)l, 16, 0, 0);
}

// ---------------- prep: build bf16 padded LDS images + permuted pair tables ----------------
// blocks 0..236: W transpose for r=bid -> Wimg[r][kh][n][72] (bf16), n=j, k-local contiguous
// blocks 237,238: E slab copy -> Eimg[slab][kh][row][72]
// blocks 239..246: permuted float2 pair tables for rel_emb and fc_w
__global__ __launch_bounds__(256) void prep(
    const float* __restrict__ ent_emb, const float* __restrict__ rel_W,
    const float* __restrict__ rel_emb, const float* __restrict__ fc_w,
    char* __restrict__ ws) {
  const int bid = blockIdx.x;
  const int t = threadIdx.x;
  __bf16* Wimg = (__bf16*)(ws + WIMG_OFF);
  __bf16* Eimg = (__bf16*)(ws + EIMG_OFF);

  if (bid < NREL) {
    __shared__ __bf16 img[2 * 128 * PITCH];            // 36 KB, exact DMA image for r
    const int kh = t >> 7;                             // 0..1
    const int n = t & 127;                             // image row = output col j
    // gather column n of W[r][kh*64 + kl][:], kl=0..63 (coalesced across lanes)
    const float* src = rel_W + ((size_t)bid * 128 + kh * 64) * 128 + n;
    __bf16* dstRow = img + (kh * 128 + n) * PITCH;
#pragma unroll
    for (int kl4 = 0; kl4 < 64; kl4 += 4) {
      float a0 = src[(kl4 + 0) * 128];
      float a1 = src[(kl4 + 1) * 128];
      float a2 = src[(kl4 + 2) * 128];
      float a3 = src[(kl4 + 3) * 128];
      bf16x4 p = {(__bf16)a0, (__bf16)a1, (__bf16)a2, (__bf16)a3};
      *(bf16x4*)(dstRow + kl4) = p;
    }
    __syncthreads();
    // coalesced flat copy out: thread t copies 144 B
    const bf16x8* s = (const bf16x8*)((const char*)img + t * 144);
    bf16x8* d = (bf16x8*)((char*)Wimg + (size_t)bid * 2 * HALF_BYTES + t * 144);
#pragma unroll
    for (int i = 0; i < 9; ++i) d[i] = s[i];
  } else if (bid < NREL + 2) {
    const int slab = bid - NREL;                       // entity rows slab*128 .. +127
#pragma unroll
    for (int i = 0; i < 16; ++i) {
      const int f = t + 256 * i;                       // float4 index, 0..4095
      const int row = f >> 5;                          // 32 float4 per row
      const int c4 = f & 31;
      float4 v = ((const float4*)(ent_emb + ((size_t)(slab * 128 + row)) * D))[c4];
      const int kh = c4 >> 4;
      const int kl = (c4 & 15) * 4;
      bf16x4 p = {(__bf16)v.x, (__bf16)v.y, (__bf16)v.z, (__bf16)v.w};
      *(bf16x4*)(Eimg + ((size_t)(slab * 2 + kh) * 128 + row) * PITCH + kl) = p;
    }
  } else {
    // permuted pair tables: fcp2[c*64+l] = {fc_w[c*128+jof(l)], fc_w[c*128+jof(l)+8]}
    //                       rep2[r*64+l] = {re[r*128+jof(l)],  re[r*128+jof(l)+8]}
    f32x2* rep2 = (f32x2*)(ws + REP2_OFF);
    f32x2* fcp2 = (f32x2*)(ws + FCP2_OFF);
    const int wq = bid - (NREL + 2);                   // 0..7
    for (int i = wq * 256 + t; i < FCP2_N + REP2_N; i += 8 * 256) {
      if (i < FCP2_N) {
        const int c = i >> 6, l = i & 63;
        const int j = jof(l);
        f32x2 v = {fc_w[c * 128 + j], fc_w[c * 128 + j + 8]};
        fcp2[i] = v;
      } else {
        const int q = i - FCP2_N;
        const int rr = q >> 6, l = q & 63;
        const int j = jof(l);
        f32x2 v = {rel_emb[rr * 128 + j], rel_emb[rr * 128 + j + 8]};
        rep2[q] = v;
      }
    }
  }
}

// ---------------- proj GEMM: pure-DMA staging, MFMA, permuted bf16 store ----------------
// block = (r, slab): 128 entity rows x 128 j. 512 threads = 8 waves x 16 rows.
__global__ __launch_bounds__(512) void proj_gemm(const char* __restrict__ ws_c,
                                                 char* __restrict__ ws) {
  const int bx = blockIdx.x;
  const int r = bx >> 1;
  const int slab = bx & 1;
  const int m0 = slab * 128;
  const int tid = threadIdx.x;
  const int wave = tid >> 6;
  const int lane = tid & 63;
  const int lrow = lane & 15;
  const int quad = lane >> 4;

  __shared__ __bf16 sE[128 * PITCH];                   // 18 KB   [row][k-local]
  __shared__ __bf16 sW[128 * PITCH];                   // 18 KB   [n][k-local]

  const char* Eimg = ws_c + EIMG_OFF;
  const char* Wimg = ws_c + WIMG_OFF;
  __bf16* proj = (__bf16*)(ws + PROJ_OFF);

  floatx4 acc[8];
#pragma unroll
  for (int tc = 0; tc < 8; ++tc) acc[tc] = (floatx4){0.f, 0.f, 0.f, 0.f};

  for (int kh = 0; kh < 2; ++kh) {
    if (kh) __syncthreads();                           // LDS reuse fence
    const char* eSrc = Eimg + (size_t)(slab * 2 + kh) * HALF_BYTES;
    const char* wSrc = Wimg + ((size_t)r * 2 + kh) * HALF_BYTES;
    for (int c = wave; c < 2 * HALF_CHUNKS; c += 8) {  // 36 x 1KB DMA chunks
      if (c < HALF_CHUNKS)
        async_cp16(eSrc + c * 1024, (char*)sE + c * 1024, lane);
      else
        async_cp16(wSrc + (c - HALF_CHUNKS) * 1024, (char*)sW + (c - HALF_CHUNKS) * 1024, lane);
    }
    __syncthreads();                                   // drains vmcnt (DMA) + barrier

#pragma unroll
    for (int kk = 0; kk < 2; ++kk) {
      const int k0 = kk * 32 + quad * 8;
      bf16x8 a = *(const bf16x8*)&sE[(wave * 16 + lrow) * PITCH + k0];
#pragma unroll
      for (int tc = 0; tc < 8; ++tc) {
        bf16x8 b = *(const bf16x8*)&sW[(tc * 16 + lrow) * PITCH + k0];
        acc[tc] = __builtin_amdgcn_mfma_f32_16x16x32_bf16(a, b, acc[tc], 0, 0, 0);
      }
    }
  }

  // store bf16, permuted: proj[r][e][lrow*8 + tc] = D[m][n=tc*16+lrow]
  const size_t rbase = (size_t)r * NENT;
#pragma unroll
  for (int reg = 0; reg < 4; ++reg) {
    const int e = m0 + wave * 16 + quad * 4 + reg;
    if (e < NENT) {
      bf16x8 v = {(__bf16)acc[0][reg], (__bf16)acc[1][reg],
                  (__bf16)acc[2][reg], (__bf16)acc[3][reg],
                  (__bf16)acc[4][reg], (__bf16)acc[5][reg],
                  (__bf16)acc[6][reg], (__bf16)acc[7][reg]};
      *(bf16x8*)(proj + (rbase + e) * D + lrow * 8) = v;
    }
  }
}

// ---------------- conv + relu + FC, packed f32x2, permuted tables ----------------
__global__ __launch_bounds__(256) void conv_fc(
    const int* __restrict__ triples, const float* __restrict__ conv_w,
    const float* __restrict__ conv_b, const float* __restrict__ fc_b,
    const char* __restrict__ ws, float* __restrict__ out) {
  const int tid = threadIdx.x;
  const int wave = tid >> 6;
  const int lane = tid & 63;
  const int b = blockIdx.x * 4 + wave;

  const __bf16* proj = (const __bf16*)(ws + PROJ_OFF);
  const f32x2* rep2 = (const f32x2*)(ws + REP2_OFF);
  const f32x2* fcp2 = (const f32x2*)(ws + FCP2_OFF);

  const int h = triples[b * 3 + 0];
  const int r = triples[b * 3 + 1];
  const int t = triples[b * 3 + 2];

  const __bf16* phr = proj + ((size_t)r * NENT + h) * D;
  const __bf16* ptr_ = proj + ((size_t)r * NENT + t) * D;

  f32x2 ph = {(float)phr[lane], (float)phr[lane + 64]};
  f32x2 pt = {(float)ptr_[lane], (float)ptr_[lane + 64]};
  f32x2 re = rep2[r * 64 + lane];

  const f32x2 zero = {0.f, 0.f};
  const f32x2* fcl = fcp2 + lane;
  f32x2 accv = {0.f, 0.f};
#pragma unroll 10
  for (int c = 0; c < 50; ++c) {
    const float w0 = conv_w[c * 3 + 0];
    const float w1 = conv_w[c * 3 + 1];
    const float w2 = conv_w[c * 3 + 2];
    const float bc = conv_b[c];
    f32x2 f = ph * w0 + re * w1 + pt * w2 + bc;
    f = __builtin_elementwise_max(f, zero);
    accv += f * fcl[c * 64];
  }
  float acc = accv.x + accv.y;
#pragma unroll
  for (int off = 32; off; off >>= 1) acc += __shfl_down(acc, off, 64);
  if (lane == 0) out[b] = acc + fc_b[0];
}

extern "C" void kernel_launch(void* const* d_in, const int* in_sizes, int n_in,
                              void* d_out, int out_size, void* d_ws, size_t ws_size,
                              hipStream_t stream) {
  const int*   triples = (const int*)  d_in[0];
  const float* ent_emb = (const float*)d_in[1];
  const float* rel_emb = (const float*)d_in[2];
  const float* rel_W   = (const float*)d_in[3];
  const float* conv_w  = (const float*)d_in[4];
  const float* conv_b  = (const float*)d_in[5];
  const float* fc_w    = (const float*)d_in[6];
  const float* fc_b    = (const float*)d_in[7];
  float* out = (float*)d_out;
  char* ws = (char*)d_ws;

  prep<<<NREL + 2 + 8, 256, 0, stream>>>(ent_emb, rel_W, rel_emb, fc_w, ws);
  proj_gemm<<<NREL * 2, 512, 0, stream>>>(ws, ws);
  conv_fc<<<B_TRIPLES / 4, 256, 0, stream>>>(triples, conv_w, conv_b, fc_b, ws, out);
}

// Round 3
// 123.096 us; speedup vs baseline: 1.0537x; 1.0537x over previous
//
#include <hip/hip_runtime.h>

typedef __bf16 bf16x8 __attribute__((ext_vector_type(8)));
typedef __bf16 bf16x4 __attribute__((ext_vector_type(4)));
typedef float  floatx4 __attribute__((ext_vector_type(4)));
typedef float  f32x2   __attribute__((ext_vector_type(2)));

#define NENT 237
#define NREL 237
#define D 128
#define B_TRIPLES 16384
#define PITCH 72                      // 64 k + 8 pad

// ws layout (bytes)
#define PROJ_OFF 0
#define PROJ_BYTES (NREL * NENT * D * 2)        // 14,379,264 (bf16, permuted j)
#define REP2_OFF PROJ_BYTES
#define REP2_N (NREL * 64)                      // f32x2 pairs
#define FCP2_OFF (REP2_OFF + REP2_N * 8)
#define FCP2_N (50 * 64)

__device__ __forceinline__ float as_f32(unsigned u) { return __builtin_bit_cast(float, u); }

// stored pos -> original j:  proj[pos = lrow*8 + tc] holds C[.., j = tc*16 + lrow]
__device__ __forceinline__ int jof(int p) { return ((p & 7) << 4) | (p >> 3); }

// ---------------- kernel 1: proj GEMM (474 blocks) + pair tables (8 blocks) ----------------
// GEMM block (r, slab): 128 entity rows x 128 j, K=128 in two 64-halves.
// W transposed in-register: 8 strided float4 loads -> 4x ds_write_b128, no global round-trip.
__global__ __launch_bounds__(256) void gemm_tables(
    const float* __restrict__ ent_emb, const float* __restrict__ rel_W,
    const float* __restrict__ rel_emb, const float* __restrict__ fc_w,
    char* __restrict__ ws) {
  const int bx = blockIdx.x;
  const int tid = threadIdx.x;

  if (bx >= 2 * NREL) {                         // ---- table blocks ----
    f32x2* rep2 = (f32x2*)(ws + REP2_OFF);
    f32x2* fcp2 = (f32x2*)(ws + FCP2_OFF);
    const int wq = bx - 2 * NREL;               // 0..7
    for (int i = wq * 256 + tid; i < (NREL + 50) * 64; i += 8 * 256) {
      const int row = i >> 6, l = i & 63;
      const int j0 = jof(2 * l), j1 = jof(2 * l + 1);
      if (row < 50) {
        f32x2 v = {fc_w[row * 128 + j0], fc_w[row * 128 + j1]};
        fcp2[i] = v;
      } else {
        const int r = row - 50;
        f32x2 v = {rel_emb[r * 128 + j0], rel_emb[r * 128 + j1]};
        rep2[r * 64 + l] = v;
      }
    }
    return;
  }

  const int r = bx >> 1;
  const int slab = bx & 1;
  const int m0 = slab * 128;
  const int wave = tid >> 6, lane = tid & 63;
  const int lrow = lane & 15, quad = lane >> 4;

  __shared__ __bf16 sE[128 * PITCH];            // [e-row][k-local]  18 KB
  __shared__ __bf16 sW[128 * PITCH];            // [n][k-local]      18 KB

  __bf16* proj = (__bf16*)(ws + PROJ_OFF);

  floatx4 acc[2][8];
#pragma unroll
  for (int tr = 0; tr < 2; ++tr)
#pragma unroll
    for (int tc = 0; tc < 8; ++tc) acc[tr][tc] = (floatx4){0.f, 0.f, 0.f, 0.f};

  const int erow = tid >> 1, eh = (tid & 1) * 32;   // sE staging coords
  const int kg = tid >> 5, ng = tid & 31;           // sW staging coords

  for (int kh = 0; kh < 2; ++kh) {
    if (kh) __syncthreads();

    // --- sE: 128 rows x 64 k, fp32->bf16 ---
    {
      const float* src = ent_emb + (size_t)(m0 + erow) * D + kh * 64 + eh;
      __bf16* dst = sE + erow * PITCH + eh;
#pragma unroll
      for (int i = 0; i < 8; ++i) {
        float4 v = ((const float4*)src)[i];
        bf16x4 p = {(__bf16)v.x, (__bf16)v.y, (__bf16)v.z, (__bf16)v.w};
        *(bf16x4*)(dst + i * 4) = p;
      }
    }
    // --- sW: in-register transpose. thread: k-rows kg*8..+7, cols ng*4..+3 ---
    {
      const float* src = rel_W + ((size_t)r * D + kh * 64 + kg * 8) * D + ng * 4;
      float col[4][8];
#pragma unroll
      for (int i = 0; i < 8; ++i) {
        float4 v = *(const float4*)(src + i * D);  // lane-coalesced 512B per row
        col[0][i] = v.x; col[1][i] = v.y; col[2][i] = v.z; col[3][i] = v.w;
      }
#pragma unroll
      for (int c = 0; c < 4; ++c) {
        bf16x8 p = {(__bf16)col[c][0], (__bf16)col[c][1], (__bf16)col[c][2],
                    (__bf16)col[c][3], (__bf16)col[c][4], (__bf16)col[c][5],
                    (__bf16)col[c][6], (__bf16)col[c][7]};
        *(bf16x8*)&sW[(ng * 4 + c) * PITCH + kg * 8] = p;  // one b128 per col
      }
    }
    __syncthreads();

    // --- MFMA: wave handles 32 e-rows (2 tr), all 128 n (8 tc) ---
#pragma unroll
    for (int kk = 0; kk < 2; ++kk) {
      const int k0 = kk * 32 + quad * 8;
      bf16x8 a[2], b[8];
#pragma unroll
      for (int tr = 0; tr < 2; ++tr)
        a[tr] = *(const bf16x8*)&sE[(wave * 32 + tr * 16 + lrow) * PITCH + k0];
#pragma unroll
      for (int tc = 0; tc < 8; ++tc)
        b[tc] = *(const bf16x8*)&sW[(tc * 16 + lrow) * PITCH + k0];
#pragma unroll
      for (int tr = 0; tr < 2; ++tr)
#pragma unroll
        for (int tc = 0; tc < 8; ++tc)
          acc[tr][tc] = __builtin_amdgcn_mfma_f32_16x16x32_bf16(
              a[tr], b[tc], acc[tr][tc], 0, 0, 0);
    }
  }

  // --- store bf16, permuted: proj[r][e][lrow*8+tc] = C[e][tc*16+lrow] ---
  const size_t rbase = (size_t)r * NENT;
#pragma unroll
  for (int tr = 0; tr < 2; ++tr) {
#pragma unroll
    for (int reg = 0; reg < 4; ++reg) {
      const int e = m0 + wave * 32 + tr * 16 + quad * 4 + reg;
      if (e < NENT) {
        bf16x8 v = {(__bf16)acc[tr][0][reg], (__bf16)acc[tr][1][reg],
                    (__bf16)acc[tr][2][reg], (__bf16)acc[tr][3][reg],
                    (__bf16)acc[tr][4][reg], (__bf16)acc[tr][5][reg],
                    (__bf16)acc[tr][6][reg], (__bf16)acc[tr][7][reg]};
        *(bf16x8*)(proj + (rbase + e) * D + lrow * 8) = v;
      }
    }
  }
}

// ---------------- kernel 2: conv + relu + FC, packed f32x2 ----------------
__global__ __launch_bounds__(256) void conv_fc(
    const int* __restrict__ triples, const float* __restrict__ conv_w,
    const float* __restrict__ conv_b, const float* __restrict__ fc_b,
    const char* __restrict__ ws, float* __restrict__ out) {
  const int tid = threadIdx.x;
  const int wave = tid >> 6, lane = tid & 63;
  const int b = blockIdx.x * 4 + wave;

  const __bf16* proj = (const __bf16*)(ws + PROJ_OFF);
  const f32x2* rep2 = (const f32x2*)(ws + REP2_OFF);
  const f32x2* fcp2 = (const f32x2*)(ws + FCP2_OFF);

  const int h = triples[b * 3 + 0];
  const int r = triples[b * 3 + 1];
  const int t = triples[b * 3 + 2];

  // one dword per entity: bf16 pair at stored pos (2*lane, 2*lane+1)
  const unsigned uh = ((const unsigned*)(proj + ((size_t)r * NENT + h) * D))[lane];
  const unsigned ut = ((const unsigned*)(proj + ((size_t)r * NENT + t) * D))[lane];
  f32x2 ph = {as_f32(uh << 16), as_f32(uh & 0xffff0000u)};
  f32x2 pt = {as_f32(ut << 16), as_f32(ut & 0xffff0000u)};
  f32x2 re = rep2[r * 64 + lane];

  const f32x2 zero = {0.f, 0.f};
  const f32x2* fcl = fcp2 + lane;
  f32x2 accv = {0.f, 0.f};
#pragma unroll 10
  for (int c = 0; c < 50; ++c) {
    const float w0 = conv_w[c * 3 + 0];
    const float w1 = conv_w[c * 3 + 1];
    const float w2 = conv_w[c * 3 + 2];
    const float bc = conv_b[c];
    f32x2 f = ph * w0 + re * w1 + pt * w2 + bc;
    f = __builtin_elementwise_max(f, zero);
    accv += f * fcl[c * 64];
  }
  float acc = accv.x + accv.y;
#pragma unroll
  for (int off = 32; off; off >>= 1) acc += __shfl_down(acc, off, 64);
  if (lane == 0) out[b] = acc + fc_b[0];
}

extern "C" void kernel_launch(void* const* d_in, const int* in_sizes, int n_in,
                              void* d_out, int out_size, void* d_ws, size_t ws_size,
                              hipStream_t stream) {
  const int*   triples = (const int*)  d_in[0];
  const float* ent_emb = (const float*)d_in[1];
  const float* rel_emb = (const float*)d_in[2];
  const float* rel_W   = (const float*)d_in[3];
  const float* conv_w  = (const float*)d_in[4];
  const float* conv_b  = (const float*)d_in[5];
  const float* fc_w    = (const float*)d_in[6];
  const float* fc_b    = (const float*)d_in[7];
  float* out = (float*)d_out;
  char* ws = (char*)d_ws;

  gemm_tables<<<2 * NREL + 8, 256, 0, stream>>>(ent_emb, rel_W, rel_emb, fc_w, ws);
  conv_fc<<<B_TRIPLES / 4, 256, 0, stream>>>(triples, conv_w, conv_b, fc_b, ws, out);
}